// Round 12
// baseline (1298.664 us; speedup 1.0000x reference)
//
#include <hip/hip_runtime.h>
#include <hip/hip_fp16.h>

#define NN 100000
#define NE 1600000
#define CC 128
#define NBIN 782      // ceil(NN/128) coarse bins (128 nodes each)
#define BPW 128       // nodes per bin
#define MAXB 2560     // bucket capacity (mean 2048, 11 sigma)
#define NHB 256       // histogram blocks
#define EPB 6250      // edges per histogram block (NE/NHB exact)

typedef _Float16 f16x8 __attribute__((ext_vector_type(8)));
typedef _Float16 f16x2 __attribute__((ext_vector_type(2)));

#if __has_builtin(__builtin_amdgcn_fdot2)
#define FDOT2(a, b, c) __builtin_amdgcn_fdot2((a), (b), (c), false)
#else
#define FDOT2(a, b, c) \
    fmaf((float)(a)[0], (float)(b)[0], fmaf((float)(a)[1], (float)(b)[1], (c)))
#endif

// ---------------- prep: coarse histograms + weight cvt + embW0 (fused) -------
__global__ __launch_bounds__(256) void k_prep0(const int* __restrict__ ei,
                                               const float* __restrict__ conv_w,
                                               const float* __restrict__ lin1_w,
                                               const float* __restrict__ emb,
                                               int* __restrict__ hist,
                                               _Float16* __restrict__ wt,
                                               __half2* __restrict__ ewh,
                                               int* __restrict__ counter) {
    int blk = blockIdx.x;
    if (blk < NHB) {
        __shared__ int h[NBIN];
        for (int i = threadIdx.x; i < NBIN; i += 256) h[i] = 0;
        __syncthreads();
        int base = blk * EPB;
        for (int i = threadIdx.x; i < EPB; i += 256) {
            int d = ei[NE + base + i];
            atomicAdd(&h[d >> 7], 1);
        }
        __syncthreads();
        for (int i = threadIdx.x; i < NBIN; i += 256)
            hist[blk * NBIN + i] = h[i];
        if (blk == 0 && threadIdx.x == 0) *counter = 0;
    } else if (blk < NHB + 192) {
        // Wt[l][j][k] = fp16(W_l[k][j])
        int t = (blk - NHB) * 256 + threadIdx.x;
        int l = t >> 14, r = t & 16383;
        int j = r >> 7, k = r & 127;
        const float* src = (l < 2) ? (conv_w + (l + 1) * 16384) : lin1_w;
        wt[l * 16384 + j * 128 + k] = (_Float16)src[k * 128 + j];
    } else {
        // ewh = fp16(emb @ W0)
        int t = (blk - NHB - 192) * 256 + threadIdx.x;
        int i = t >> 6, jp = t & 63, j0 = jp * 2;
        float a0 = 0.f, a1 = 0.f;
        for (int k = 0; k < 128; k++) {
            float e = emb[i * 128 + k];
            a0 = fmaf(e, conv_w[k * 128 + j0], a0);
            a1 = fmaf(e, conv_w[k * 128 + j0 + 1], a1);
        }
        ewh[t] = __floats2half2_rn(a0, a1);
    }
}

// ---------------- scan A (+ fused final scan via last-block trick) ----------
__global__ __launch_bounds__(256) void k_scanA(const int* __restrict__ hist,
                                               int* __restrict__ blockBase,
                                               int* __restrict__ binTotal,
                                               int* __restrict__ binStart,
                                               int* __restrict__ counter) {
    __shared__ int s[256];
    __shared__ bool amLast;
    int bin = blockIdx.x, t = threadIdx.x;
    int v = hist[t * NBIN + bin];
    s[t] = v; __syncthreads();
    for (int off = 1; off < 256; off <<= 1) {
        int x = (t >= off) ? s[t - off] : 0;
        __syncthreads();
        s[t] += x;
        __syncthreads();
    }
    blockBase[t * NBIN + bin] = s[t] - v;   // exclusive within bin
    if (t == 255) {
        binTotal[bin] = s[255];
        __threadfence();
        int d = atomicAdd(counter, 1);
        amLast = (d == NBIN - 1);
    }
    __syncthreads();
    if (!amLast) return;
    // final exclusive scan over binTotal[0..NBIN-1]
    int loc[4];
    int sum = 0;
#pragma unroll
    for (int j = 0; j < 4; j++) {
        int idx = t * 4 + j;
        int x = (idx < NBIN) ? atomicAdd(&binTotal[idx], 0) : 0;  // coherent read
        loc[j] = sum; sum += x;
    }
    __syncthreads();
    s[t] = sum; __syncthreads();
    for (int off = 1; off < 256; off <<= 1) {
        int x = (t >= off) ? s[t - off] : 0;
        __syncthreads();
        s[t] += x;
        __syncthreads();
    }
    int base = s[t] - sum;
#pragma unroll
    for (int j = 0; j < 4; j++) {
        int idx = t * 4 + j;
        if (idx < NBIN) binStart[idx] = base + loc[j];
    }
    if (t == 255) binStart[NBIN] = s[255];   // == NE
}

// ---------------- pass 2: scatter edges into coarse buckets (LDS ranks) -----
__global__ __launch_bounds__(256) void k_pass2(const int* __restrict__ ei,
                                               const float* __restrict__ ew,
                                               const int* __restrict__ binStart,
                                               const int* __restrict__ blockBase,
                                               int2* __restrict__ pay,
                                               unsigned char* __restrict__ key) {
    __shared__ int cur[NBIN];
    int blk = blockIdx.x;
    for (int i = threadIdx.x; i < NBIN; i += 256)
        cur[i] = binStart[i] + blockBase[blk * NBIN + i];
    __syncthreads();
    int base = blk * EPB;
    for (int i = threadIdx.x; i < EPB; i += 256) {
        int e = base + i;
        int d = ei[NE + e];
        int src = ei[e];
        float w = ew[e];
        int pos = atomicAdd(&cur[d >> 7], 1);
        pay[pos] = make_int2(src, __float_as_int(w));
        key[pos] = (unsigned char)(d & 127);
    }
}

// ---------------- pass 3: per-bucket local sort -> CSR + rowptr + dinv ------
__global__ __launch_bounds__(256) void k_pass3(const int* __restrict__ binStart,
                                               const int2* __restrict__ pay,
                                               const unsigned char* __restrict__ key,
                                               int2* __restrict__ csr,
                                               int* __restrict__ rowptr,
                                               float* __restrict__ dinv) {
    __shared__ int2 sp[MAXB];
    __shared__ unsigned char sk[MAXB];
    __shared__ int hist[BPW], excl[BPW], cur[BPW];
    __shared__ float degw[BPW];
    int b = blockIdx.x, t = threadIdx.x;
    int s0 = binStart[b], s1 = binStart[b + 1];
    int n = s1 - s0;
    if (t < BPW) { hist[t] = 0; degw[t] = 0.f; }
    __syncthreads();
    for (int i = t; i < n; i += 256) {
        int2 p = pay[s0 + i];
        unsigned char k = key[s0 + i];
        sp[i] = p; sk[i] = k;
        atomicAdd(&hist[k], 1);
    }
    __syncthreads();
    if (t < BPW) excl[t] = hist[t];
    __syncthreads();
    for (int off = 1; off < BPW; off <<= 1) {
        int x = (t < BPW && t >= off) ? excl[t - off] : 0;
        __syncthreads();
        if (t < BPW) excl[t] += x;
        __syncthreads();
    }
    if (t < BPW) {
        int ex = excl[t] - hist[t];
        excl[t] = ex;
        cur[t] = ex;
    }
    __syncthreads();
    int node0 = b * BPW;
    if (t < BPW && node0 + t < NN) rowptr[node0 + t] = s0 + excl[t];
    if (b == NBIN - 1 && t == 0) rowptr[NN] = NE;
    for (int i = t; i < n; i += 256) {
        int2 p = sp[i];
        unsigned char k = sk[i];
        int pos = atomicAdd(&cur[k], 1);
        csr[s0 + pos] = p;
        atomicAdd(&degw[k], __int_as_float(p.y));
    }
    __syncthreads();
    if (t < BPW && node0 + t < NN) dinv[node0 + t] = rsqrtf(1.f + degw[t]);
}

// csr0[pos] = {emb_row(src), w*dinv[src]}
__global__ void k_mkcsr0(const int2* __restrict__ csr, const int* __restrict__ xidx,
                         const float* __restrict__ dinv, int2* __restrict__ csr0) {
    int e = blockIdx.x * 256 + threadIdx.x;
    if (e < NE) {
        int2 c = csr[e];
        csr0[e] = make_int2(xidx[c.x],
                            __float_as_int(__int_as_float(c.y) * dinv[c.x]));
    }
}

// ---------------- fused agg + per-wave GEMM epilogue -------------------------
// Gather phase: R6-proven structure, ONE NODE PER WAVE (full concurrency),
// wave = 4 groups x 16 lanes, 8-wide main loop, guarded 4-wide tail.
// Epilogue: group-0 writes x-row (fp16) to per-wave LDS; after one barrier all
// 64 lanes compute 2 output channels each via v_dot2 against L1-resident Wt.
// HEAD=0: yout[v][j] = fp16(dinv[v] * (x @ W)[j])
// HEAD=1: h = relu(x @ lin1 + hb); outf[v][0:2] = h @ w2 + b2
template <int SELF_TABLE, int RELU, int HEAD>
__global__ __launch_bounds__(256) void k_aggmm(const _Float16* __restrict__ src16,
                                               const int2* __restrict__ csr,
                                               const int* __restrict__ rowptr,
                                               const int* __restrict__ xidx,
                                               const float* __restrict__ dinv,
                                               const float* __restrict__ bias,
                                               const _Float16* __restrict__ Wt,
                                               _Float16* __restrict__ yout,
                                               const float* __restrict__ hb,
                                               const float* __restrict__ w2,
                                               const float* __restrict__ b2,
                                               float* __restrict__ outf) {
    __shared__ _Float16 xs[4][128];
    int wave = threadIdx.x >> 6, lane = threadIdx.x & 63;
    int g = lane >> 4, sub = lane & 15;
    int v = blockIdx.x * 4 + wave;          // grid = NN/4 exact, v < NN always
    int beg = rowptr[v], end = rowptr[v + 1];
    float acc[8];
#pragma unroll
    for (int i = 0; i < 8; i++) acc[i] = 0.f;
    int e = beg;
    while (e + 8 <= end) {
        int2 c0 = csr[e + g];
        int2 c1 = csr[e + 4 + g];
        f16x8 t0 = *reinterpret_cast<const f16x8*>(&src16[(size_t)c0.x * 128 + sub * 8]);
        f16x8 t1 = *reinterpret_cast<const f16x8*>(&src16[(size_t)c1.x * 128 + sub * 8]);
        float w0 = __int_as_float(c0.y), w1 = __int_as_float(c1.y);
#pragma unroll
        for (int i = 0; i < 8; i++) acc[i] = fmaf(w0, (float)t0[i], acc[i]);
#pragma unroll
        for (int i = 0; i < 8; i++) acc[i] = fmaf(w1, (float)t1[i], acc[i]);
        e += 8;
    }
    for (; e < end; e += 4) {
        int idx = e + g;
        bool ok = idx < end;
        int2 c0 = csr[ok ? idx : beg];
        float w0 = ok ? __int_as_float(c0.y) : 0.f;
        f16x8 t0 = *reinterpret_cast<const f16x8*>(&src16[(size_t)c0.x * 128 + sub * 8]);
#pragma unroll
        for (int i = 0; i < 8; i++) acc[i] = fmaf(w0, (float)t0[i], acc[i]);
    }
#pragma unroll
    for (int i = 0; i < 8; i++) {
        acc[i] += __shfl_down(acc[i], 32);
        acc[i] += __shfl_down(acc[i], 16);
    }
    if (g == 0) {
        float dv = dinv[v];
        size_t selfoff = SELF_TABLE ? (size_t)xidx[v] * 128 : (size_t)v * 128;
        f16x8 sf = *reinterpret_cast<const f16x8*>(&src16[selfoff + sub * 8]);
        float4 b0 = reinterpret_cast<const float4*>(bias)[sub * 2];
        float4 b1 = reinterpret_cast<const float4*>(bias)[sub * 2 + 1];
        float bb[8] = {b0.x, b0.y, b0.z, b0.w, b1.x, b1.y, b1.z, b1.w};
        f16x8 o;
#pragma unroll
        for (int i = 0; i < 8; i++) {
            float self = SELF_TABLE ? dv * (float)sf[i] : (float)sf[i];
            float r = fmaf(dv, acc[i] + self, bb[i]);
            if (RELU) r = fmaxf(r, 0.f);
            o[i] = (_Float16)r;
        }
        *reinterpret_cast<f16x8*>(&xs[wave][sub * 8]) = o;
    }
    __syncthreads();

    // ---- per-wave GEMM epilogue: 2 output channels per lane ----
    int j0 = lane * 2;
    const _Float16* w0p = &Wt[(size_t)j0 * 128];
    const _Float16* w1p = w0p + 128;
    float p0 = 0.f, p1 = 0.f;
#pragma unroll
    for (int kc = 0; kc < 16; kc++) {
        f16x8 xv = *reinterpret_cast<const f16x8*>(&xs[wave][kc * 8]);
        f16x8 wa = *reinterpret_cast<const f16x8*>(&w0p[kc * 8]);
        f16x8 wb = *reinterpret_cast<const f16x8*>(&w1p[kc * 8]);
#pragma unroll
        for (int q = 0; q < 4; q++) {
            f16x2 xp = {xv[2 * q], xv[2 * q + 1]};
            f16x2 ap = {wa[2 * q], wa[2 * q + 1]};
            f16x2 bp = {wb[2 * q], wb[2 * q + 1]};
            p0 = FDOT2(xp, ap, p0);
            p1 = FDOT2(xp, bp, p1);
        }
    }
    if (HEAD == 0) {
        float dv = dinv[v];
        __half2 r = __floats2half2_rn(dv * p0, dv * p1);
        *reinterpret_cast<__half2*>(&yout[(size_t)v * 128 + j0]) = r;
    } else {
        float h0 = fmaxf(p0 + hb[j0], 0.f);
        float h1 = fmaxf(p1 + hb[j0 + 1], 0.f);
        float q0 = fmaf(h0, w2[j0 * 2 + 0], h1 * w2[(j0 + 1) * 2 + 0]);
        float q1 = fmaf(h0, w2[j0 * 2 + 1], h1 * w2[(j0 + 1) * 2 + 1]);
#pragma unroll
        for (int m = 32; m; m >>= 1) {
            q0 += __shfl_down(q0, m);
            q1 += __shfl_down(q1, m);
        }
        if (lane == 0)
            *reinterpret_cast<float2*>(&outf[(size_t)v * 2]) =
                make_float2(q0 + b2[0], q1 + b2[1]);
    }
}

extern "C" void kernel_launch(void* const* d_in, const int* in_sizes, int n_in,
                              void* d_out, int out_size, void* d_ws, size_t ws_size,
                              hipStream_t stream) {
    const int*   x_idx  = (const int*)d_in[0];
    const int*   ei     = (const int*)d_in[1];
    const float* ew     = (const float*)d_in[2];
    const float* emb    = (const float*)d_in[3];
    const float* conv_w = (const float*)d_in[4];
    const float* conv_b = (const float*)d_in[5];
    const float* lin1_w = (const float*)d_in[6];
    const float* lin1_b = (const float*)d_in[7];
    const float* lin2_w = (const float*)d_in[8];
    const float* lin2_b = (const float*)d_in[9];
    float* out = (float*)d_out;

    char* ws = (char*)d_ws;
    size_t off = 0;
    auto alloc = [&](size_t bytes) -> void* {
        void* p = ws + off;
        off += (bytes + 255) & ~(size_t)255;
        return p;
    };
    float*         dinv      = (float*)alloc(NN * 4);
    int*           rowptr    = (int*)alloc((NN + 1) * 4);
    int*           hist      = (int*)alloc((size_t)NHB * NBIN * 4);
    int*           blockBase = (int*)alloc((size_t)NHB * NBIN * 4);
    int*           binTotal  = (int*)alloc(NBIN * 4);
    int*           binStart  = (int*)alloc((NBIN + 1) * 4);
    int*           counter   = (int*)alloc(256);
    int2*          pay       = (int2*)alloc((size_t)NE * 8);
    unsigned char* key       = (unsigned char*)alloc(NE);
    int2*          csr       = (int2*)alloc((size_t)NE * 8);
    int2*          csr0      = (int2*)alloc((size_t)NE * 8);
    _Float16*      ewh       = (_Float16*)alloc(128 * 128 * 2);
    _Float16*      wt        = (_Float16*)alloc(3 * 128 * 128 * 2);
    _Float16*      ybufA     = (_Float16*)alloc((size_t)NN * CC * 2);
    _Float16*      ybufB     = (_Float16*)alloc((size_t)NN * CC * 2);
    (void)ws_size;

    const int NBe = (NE + 255) / 256;       // 6250

    // CSR build: 2-level counting sort, no global atomics
    k_prep0<<<NHB + 192 + 32, 256, 0, stream>>>(ei, conv_w, lin1_w, emb,
                                                hist, wt, (__half2*)ewh, counter);
    k_scanA<<<NBIN, 256, 0, stream>>>(hist, blockBase, binTotal, binStart, counter);
    k_pass2<<<NHB, 256, 0, stream>>>(ei, ew, binStart, blockBase, pay, key);
    k_pass3<<<NBIN, 256, 0, stream>>>(binStart, pay, key, csr, rowptr, dinv);
    k_mkcsr0<<<NBe, 256, 0, stream>>>(csr, x_idx, dinv, csr0);

    // fused layer 0 agg (L1-table gather) + GEMM W1: ybufA = dinv*(x1 @ W1)
    k_aggmm<1, 1, 0><<<NN / 4, 256, 0, stream>>>(ewh, csr0, rowptr, x_idx, dinv,
                                                 conv_b + 0 * CC, wt + 0 * 16384,
                                                 ybufA, nullptr, nullptr, nullptr,
                                                 nullptr);
    // fused layer 1 agg + GEMM W2: ybufB = dinv*(x2 @ W2)
    k_aggmm<0, 1, 0><<<NN / 4, 256, 0, stream>>>(ybufA, csr, rowptr, nullptr, dinv,
                                                 conv_b + 1 * CC, wt + 1 * 16384,
                                                 ybufB, nullptr, nullptr, nullptr,
                                                 nullptr);
    // fused layer 2 agg + head: out = relu(x3 @ lin1 + b) @ lin2 + b2
    k_aggmm<0, 0, 1><<<NN / 4, 256, 0, stream>>>(ybufB, csr, rowptr, nullptr, dinv,
                                                 conv_b + 2 * CC, wt + 2 * 16384,
                                                 nullptr, lin1_b, lin2_w, lin2_b,
                                                 out);
}

// Round 13
// 390.556 us; speedup vs baseline: 3.3252x; 3.3252x over previous
//
#include <hip/hip_runtime.h>
#include <hip/hip_fp16.h>

#define NN 100000
#define NE 1600000
#define CC 128
#define NBIN 782      // ceil(NN/128) coarse bins (128 nodes each)
#define BPW 128       // nodes per bin
#define MAXB 2560     // bucket capacity (mean 2048, sigma ~45 -> 11 sigma)
#define NHB 256       // histogram blocks
#define EPB 6250      // edges per histogram block (NE/NHB exact)

typedef _Float16 f16x8 __attribute__((ext_vector_type(8)));
typedef float    f32x4 __attribute__((ext_vector_type(4)));

// ---------------- pass 1: per-block coarse histograms (no global atomics) ----
__global__ __launch_bounds__(256) void k_hist(const int* __restrict__ ei,
                                              int* __restrict__ hist) {
    __shared__ int h[NBIN];
    for (int i = threadIdx.x; i < NBIN; i += 256) h[i] = 0;
    __syncthreads();
    int base = blockIdx.x * EPB;
    for (int i = threadIdx.x; i < EPB; i += 256) {
        int d = ei[NE + base + i];
        atomicAdd(&h[d >> 7], 1);
    }
    __syncthreads();
    for (int i = threadIdx.x; i < NBIN; i += 256)
        hist[blockIdx.x * NBIN + i] = h[i];
}

// ---------------- scan A: per bin, scan counts across the 256 blocks --------
__global__ __launch_bounds__(256) void k_scanA(const int* __restrict__ hist,
                                               int* __restrict__ blockBase,
                                               int* __restrict__ binTotal) {
    __shared__ int s[256];
    int bin = blockIdx.x, t = threadIdx.x;
    int v = hist[t * NBIN + bin];
    s[t] = v; __syncthreads();
    for (int off = 1; off < 256; off <<= 1) {
        int x = (t >= off) ? s[t - off] : 0;
        __syncthreads();
        s[t] += x;
        __syncthreads();
    }
    blockBase[t * NBIN + bin] = s[t] - v;   // exclusive within bin
    if (t == 255) binTotal[bin] = s[255];
}

// ---------------- scan B: exclusive scan over bin totals ----------------
__global__ __launch_bounds__(1024) void k_scanB(const int* __restrict__ binTotal,
                                                int* __restrict__ binStart) {
    __shared__ int s[1024];
    int t = threadIdx.x;
    int v = (t < NBIN) ? binTotal[t] : 0;
    s[t] = v; __syncthreads();
    for (int off = 1; off < 1024; off <<= 1) {
        int x = (t >= off) ? s[t - off] : 0;
        __syncthreads();
        s[t] += x;
        __syncthreads();
    }
    if (t < NBIN) binStart[t] = s[t] - v;
    if (t == 1023) binStart[NBIN] = s[1023];   // == NE
}

// ---------------- pass 2: scatter edges into coarse buckets (LDS ranks) -----
__global__ __launch_bounds__(256) void k_pass2(const int* __restrict__ ei,
                                               const float* __restrict__ ew,
                                               const int* __restrict__ binStart,
                                               const int* __restrict__ blockBase,
                                               int2* __restrict__ pay,
                                               unsigned char* __restrict__ key) {
    __shared__ int cur[NBIN];
    int blk = blockIdx.x;
    for (int i = threadIdx.x; i < NBIN; i += 256)
        cur[i] = binStart[i] + blockBase[blk * NBIN + i];
    __syncthreads();
    int base = blk * EPB;
    for (int i = threadIdx.x; i < EPB; i += 256) {
        int e = base + i;
        int d = ei[NE + e];
        int src = ei[e];
        float w = ew[e];
        int pos = atomicAdd(&cur[d >> 7], 1);
        pay[pos] = make_int2(src, __float_as_int(w));
        key[pos] = (unsigned char)(d & 127);
    }
}

// ---------------- pass 3: per-bucket local sort -> CSR + rowptr + dinv ------
__global__ __launch_bounds__(256) void k_pass3(const int* __restrict__ binStart,
                                               const int2* __restrict__ pay,
                                               const unsigned char* __restrict__ key,
                                               int2* __restrict__ csr,
                                               int* __restrict__ rowptr,
                                               float* __restrict__ dinv) {
    __shared__ int2 sp[MAXB];
    __shared__ unsigned char sk[MAXB];
    __shared__ int hist[BPW], excl[BPW], cur[BPW];
    __shared__ float degw[BPW];
    int b = blockIdx.x, t = threadIdx.x;
    int s0 = binStart[b], s1 = binStart[b + 1];
    int n = s1 - s0;
    if (t < BPW) { hist[t] = 0; degw[t] = 0.f; }
    __syncthreads();
    for (int i = t; i < n; i += 256) {
        int2 p = pay[s0 + i];
        unsigned char k = key[s0 + i];
        sp[i] = p; sk[i] = k;
        atomicAdd(&hist[k], 1);
    }
    __syncthreads();
    if (t < BPW) excl[t] = hist[t];
    __syncthreads();
    for (int off = 1; off < BPW; off <<= 1) {
        int x = (t < BPW && t >= off) ? excl[t - off] : 0;
        __syncthreads();
        if (t < BPW) excl[t] += x;
        __syncthreads();
    }
    if (t < BPW) {
        int ex = excl[t] - hist[t];
        excl[t] = ex;
        cur[t] = ex;
    }
    __syncthreads();
    int node0 = b * BPW;
    if (t < BPW && node0 + t < NN) rowptr[node0 + t] = s0 + excl[t];
    if (b == NBIN - 1 && t == 0) rowptr[NN] = NE;
    for (int i = t; i < n; i += 256) {
        int2 p = sp[i];
        unsigned char k = sk[i];
        int pos = atomicAdd(&cur[k], 1);
        csr[s0 + pos] = p;
        atomicAdd(&degw[k], __int_as_float(p.y));
    }
    __syncthreads();
    if (t < BPW && node0 + t < NN) dinv[node0 + t] = rsqrtf(1.f + degw[t]);
}

// csr0[pos] = {emb_row(src), w*dinv[src]}
__global__ void k_mkcsr0(const int2* __restrict__ csr, const int* __restrict__ xidx,
                         const float* __restrict__ dinv, int2* __restrict__ csr0) {
    int e = blockIdx.x * 256 + threadIdx.x;
    if (e < NE) {
        int2 c = csr[e];
        csr0[e] = make_int2(xidx[c.x],
                            __float_as_int(__int_as_float(c.y) * dinv[c.x]));
    }
}

// Wt[l][j][k] = fp16(W_l[k][j])  (transposed fp16 weights for MFMA B-fragments)
__global__ void k_wcvt(const float* __restrict__ conv_w, const float* __restrict__ lin1_w,
                       _Float16* __restrict__ wt) {
    int t = blockIdx.x * 256 + threadIdx.x;  // 3*16384
    int l = t >> 14, r = t & 16383;
    int j = r >> 7, k = r & 127;
    const float* src = (l < 2) ? (conv_w + (l + 1) * 16384) : lin1_w;
    wt[l * 16384 + j * 128 + k] = (_Float16)src[k * 128 + j];
}

// ---------------- embW0 = emb @ W0, stored fp16 (32KB, L1-resident) ----------
__global__ void k_embw(const float* __restrict__ emb, const float* __restrict__ w0,
                       __half2* __restrict__ ewh) {
    int t = blockIdx.x * 256 + threadIdx.x;  // 8192 threads
    int i = t >> 6, jp = t & 63;
    int j0 = jp * 2;
    float a0 = 0.f, a1 = 0.f;
    for (int k = 0; k < 128; k++) {
        float e = emb[i * 128 + k];
        a0 = fmaf(e, w0[k * 128 + j0], a0);
        a1 = fmaf(e, w0[k * 128 + j0 + 1], a1);
    }
    ewh[t] = __floats2half2_rn(a0, a1);
}

// ---------------- quad-edge aggregation core (best-measured R6 form) --------
// Wave = 4 groups x 16 lanes; group g handles one edge, lane loads 16B of the
// 256B source row. Main loop 8-wide (2 gathers in flight), guarded 4-wide tail.
template <int SELF_TABLE, int RELU>
__device__ __forceinline__ void agg_core(const _Float16* __restrict__ src16,
                                         const int2* __restrict__ csr,
                                         const int* __restrict__ rowptr,
                                         const int* __restrict__ xidx,
                                         const float* __restrict__ dinv,
                                         const float* __restrict__ bias,
                                         _Float16* __restrict__ xout) {
    int wave = threadIdx.x >> 6, lane = threadIdx.x & 63;
    int g = lane >> 4, sub = lane & 15;
    int v = blockIdx.x * 4 + wave;
    if (v >= NN) return;
    int beg = rowptr[v], end = rowptr[v + 1];
    float acc[8];
#pragma unroll
    for (int i = 0; i < 8; i++) acc[i] = 0.f;
    int e = beg;
    while (e + 8 <= end) {
        int2 c0 = csr[e + g];
        int2 c1 = csr[e + 4 + g];
        f16x8 t0 = *reinterpret_cast<const f16x8*>(&src16[(size_t)c0.x * 128 + sub * 8]);
        f16x8 t1 = *reinterpret_cast<const f16x8*>(&src16[(size_t)c1.x * 128 + sub * 8]);
        float w0 = __int_as_float(c0.y), w1 = __int_as_float(c1.y);
#pragma unroll
        for (int i = 0; i < 8; i++) acc[i] = fmaf(w0, (float)t0[i], acc[i]);
#pragma unroll
        for (int i = 0; i < 8; i++) acc[i] = fmaf(w1, (float)t1[i], acc[i]);
        e += 8;
    }
    for (; e < end; e += 4) {
        int idx = e + g;
        bool ok = idx < end;
        int2 c0 = csr[ok ? idx : beg];
        float w0 = ok ? __int_as_float(c0.y) : 0.f;
        f16x8 t0 = *reinterpret_cast<const f16x8*>(&src16[(size_t)c0.x * 128 + sub * 8]);
#pragma unroll
        for (int i = 0; i < 8; i++) acc[i] = fmaf(w0, (float)t0[i], acc[i]);
    }
#pragma unroll
    for (int i = 0; i < 8; i++) {
        acc[i] += __shfl_down(acc[i], 32);
        acc[i] += __shfl_down(acc[i], 16);
    }
    if (g == 0) {
        float dv = dinv[v];
        size_t selfoff = SELF_TABLE ? (size_t)xidx[v] * 128 : (size_t)v * 128;
        f16x8 sf = *reinterpret_cast<const f16x8*>(&src16[selfoff + sub * 8]);
        float4 b0 = reinterpret_cast<const float4*>(bias)[sub * 2];
        float4 b1 = reinterpret_cast<const float4*>(bias)[sub * 2 + 1];
        float bb[8] = {b0.x, b0.y, b0.z, b0.w, b1.x, b1.y, b1.z, b1.w};
        f16x8 o;
#pragma unroll
        for (int i = 0; i < 8; i++) {
            float self = SELF_TABLE ? dv * (float)sf[i] : (float)sf[i];
            float r = fmaf(dv, acc[i] + self, bb[i]);
            if (RELU) r = fmaxf(r, 0.f);
            o[i] = (_Float16)r;
        }
        *reinterpret_cast<f16x8*>(&xout[(size_t)v * 128 + sub * 8]) = o;
    }
}

__global__ void k_agg0(const int2* __restrict__ csr0, const int* __restrict__ rowptr,
                       const int* __restrict__ xidx, const float* __restrict__ dinv,
                       const _Float16* __restrict__ ewh, const float* __restrict__ bias,
                       _Float16* __restrict__ xout) {
    agg_core<1, 1>(ewh, csr0, rowptr, xidx, dinv, bias, xout);
}

__global__ void k_agg_r(const _Float16* __restrict__ y, const int* __restrict__ rowptr,
                        const int2* __restrict__ csr, const float* __restrict__ dinv,
                        const float* __restrict__ bias, _Float16* __restrict__ xout) {
    agg_core<0, 1>(y, csr, rowptr, nullptr, dinv, bias, xout);
}

__global__ void k_agg_n(const _Float16* __restrict__ y, const int* __restrict__ rowptr,
                        const int2* __restrict__ csr, const float* __restrict__ dinv,
                        const float* __restrict__ bias, _Float16* __restrict__ xout) {
    agg_core<0, 0>(y, csr, rowptr, nullptr, dinv, bias, xout);
}

// ---------------- MFMA fp16 GEMM: 64 rows/block, 4 waves, 16 rows/wave -------
// MODE 0: y[n][j] = fp16( dinv[n] * (A@W)[n][j] )
// MODE 1: h = relu(A@W + bias); out[n][0:2] = h @ w2 + b2
template <int MODE>
__global__ __launch_bounds__(256) void k_mgemm(const _Float16* __restrict__ A,
                                               const _Float16* __restrict__ Wt,
                                               const float* __restrict__ dinv,
                                               const float* __restrict__ bias,
                                               _Float16* __restrict__ yout,
                                               const float* __restrict__ w2,
                                               const float* __restrict__ b2,
                                               float* __restrict__ outf) {
    int wid = threadIdx.x >> 6, lane = threadIdx.x & 63;
    int lc = lane & 15, lg = lane >> 4;
    int arow = blockIdx.x * 64 + wid * 16 + lc;   // row this lane loads for A
    bool rok = arow < NN;

    f32x4 acc[8];
#pragma unroll
    for (int j = 0; j < 8; j++) acc[j] = (f32x4){0.f, 0.f, 0.f, 0.f};

#pragma unroll
    for (int kc = 0; kc < 4; kc++) {
        int k0 = kc * 32 + lg * 8;
        f16x8 a = {0, 0, 0, 0, 0, 0, 0, 0};
        if (rok) a = *reinterpret_cast<const f16x8*>(&A[arow * 128 + k0]);
#pragma unroll
        for (int j = 0; j < 8; j++) {
            f16x8 b = *reinterpret_cast<const f16x8*>(&Wt[(j * 16 + lc) * 128 + k0]);
            acc[j] = __builtin_amdgcn_mfma_f32_16x16x32_f16(a, b, acc[j], 0, 0, 0);
        }
    }

    int orow0 = blockIdx.x * 64 + wid * 16 + lg * 4;  // rows for regs r=0..3
    if (MODE == 0) {
        float dv[4];
#pragma unroll
        for (int r = 0; r < 4; r++)
            dv[r] = (orow0 + r < NN) ? dinv[orow0 + r] : 0.f;
#pragma unroll
        for (int j = 0; j < 8; j++) {
#pragma unroll
            for (int r = 0; r < 4; r++) {
                int orow = orow0 + r;
                if (orow < NN)
                    yout[orow * 128 + j * 16 + lc] = (_Float16)(dv[r] * acc[j][r]);
            }
        }
    } else {
        float bj[8], w0j[8], w1j[8];
#pragma unroll
        for (int j = 0; j < 8; j++) {
            int c = j * 16 + lc;
            bj[j] = bias[c];
            w0j[j] = w2[c * 2 + 0];
            w1j[j] = w2[c * 2 + 1];
        }
        float bb0 = b2[0], bb1 = b2[1];
#pragma unroll
        for (int r = 0; r < 4; r++) {
            float p0 = 0.f, p1 = 0.f;
#pragma unroll
            for (int j = 0; j < 8; j++) {
                float h = fmaxf(acc[j][r] + bj[j], 0.f);
                p0 = fmaf(h, w0j[j], p0);
                p1 = fmaf(h, w1j[j], p1);
            }
#pragma unroll
            for (int m = 1; m < 16; m <<= 1) {
                p0 += __shfl_xor(p0, m);
                p1 += __shfl_xor(p1, m);
            }
            int orow = orow0 + r;
            if (lc == 0 && orow < NN)
                *reinterpret_cast<float2*>(&outf[orow * 2]) =
                    make_float2(p0 + bb0, p1 + bb1);
        }
    }
}

extern "C" void kernel_launch(void* const* d_in, const int* in_sizes, int n_in,
                              void* d_out, int out_size, void* d_ws, size_t ws_size,
                              hipStream_t stream) {
    const int*   x_idx  = (const int*)d_in[0];
    const int*   ei     = (const int*)d_in[1];
    const float* ew     = (const float*)d_in[2];
    const float* emb    = (const float*)d_in[3];
    const float* conv_w = (const float*)d_in[4];
    const float* conv_b = (const float*)d_in[5];
    const float* lin1_w = (const float*)d_in[6];
    const float* lin1_b = (const float*)d_in[7];
    const float* lin2_w = (const float*)d_in[8];
    const float* lin2_b = (const float*)d_in[9];
    float* out = (float*)d_out;

    char* ws = (char*)d_ws;
    size_t off = 0;
    auto alloc = [&](size_t bytes) -> void* {
        void* p = ws + off;
        off += (bytes + 255) & ~(size_t)255;
        return p;
    };
    float*         dinv      = (float*)alloc(NN * 4);
    int*           rowptr    = (int*)alloc((NN + 1) * 4);
    int*           hist      = (int*)alloc((size_t)NHB * NBIN * 4);
    int*           blockBase = (int*)alloc((size_t)NHB * NBIN * 4);
    int*           binTotal  = (int*)alloc(NBIN * 4);
    int*           binStart  = (int*)alloc((NBIN + 1) * 4);
    int2*          pay       = (int2*)alloc((size_t)NE * 8);
    unsigned char* key       = (unsigned char*)alloc(NE);
    int2*          csr       = (int2*)alloc((size_t)NE * 8);
    int2*          csr0      = (int2*)alloc((size_t)NE * 8);
    _Float16*      ewh       = (_Float16*)alloc(128 * 128 * 2);
    _Float16*      wt        = (_Float16*)alloc(3 * 128 * 128 * 2);
    _Float16*      xbuf      = (_Float16*)alloc((size_t)NN * CC * 2);
    _Float16*      ybuf      = (_Float16*)alloc((size_t)NN * CC * 2);
    (void)ws_size;

    const int NBe = (NE + 255) / 256;       // 6250
    const int NBg = (NN + 63) / 64;         // 1563

    // CSR build: 2-level counting sort, no global atomics
    k_hist<<<NHB, 256, 0, stream>>>(ei, hist);
    k_scanA<<<NBIN, 256, 0, stream>>>(hist, blockBase, binTotal);
    k_scanB<<<1, 1024, 0, stream>>>(binTotal, binStart);
    k_pass2<<<NHB, 256, 0, stream>>>(ei, ew, binStart, blockBase, pay, key);
    k_pass3<<<NBIN, 256, 0, stream>>>(binStart, pay, key, csr, rowptr, dinv);
    k_mkcsr0<<<NBe, 256, 0, stream>>>(csr, x_idx, dinv, csr0);
    k_wcvt<<<192, 256, 0, stream>>>(conv_w, lin1_w, wt);

    // layer 0: ewh = fp16(emb @ W0); fused gather-aggregate from L1 table
    k_embw<<<32, 256, 0, stream>>>(emb, conv_w, (__half2*)ewh);
    k_agg0<<<NN / 4, 256, 0, stream>>>(csr0, rowptr, x_idx, dinv, ewh,
                                       conv_b + 0 * CC, xbuf);
    // layer 1
    k_mgemm<0><<<NBg, 256, 0, stream>>>(xbuf, wt + 0 * 16384, dinv, nullptr, ybuf,
                                        nullptr, nullptr, nullptr);
    k_agg_r<<<NN / 4, 256, 0, stream>>>(ybuf, rowptr, csr, dinv, conv_b + 1 * CC, xbuf);
    // layer 2
    k_mgemm<0><<<NBg, 256, 0, stream>>>(xbuf, wt + 1 * 16384, dinv, nullptr, ybuf,
                                        nullptr, nullptr, nullptr);
    k_agg_n<<<NN / 4, 256, 0, stream>>>(ybuf, rowptr, csr, dinv, conv_b + 2 * CC, xbuf);
    // head: relu(x @ lin1_w + lin1_b) @ lin2_w + lin2_b, fused, MFMA
    k_mgemm<1><<<NBg, 256, 0, stream>>>(xbuf, wt + 2 * 16384, dinv, lin1_b, nullptr,
                                        lin2_w, lin2_b, out);
}

// Round 14
// 368.159 us; speedup vs baseline: 3.5275x; 1.0608x over previous
//
#include <hip/hip_runtime.h>
#include <hip/hip_fp16.h>

#define NN 100000
#define NE 1600000
#define CC 128
#define NBIN 782      // ceil(NN/128) coarse bins (128 nodes each)
#define BPW 128       // nodes per bin
#define MAXB 2560     // bucket capacity (mean 2048, sigma ~45 -> 11 sigma)
#define NHB 256       // histogram blocks
#define EPB 6250      // edges per histogram block (NE/NHB exact)

typedef _Float16 f16x8 __attribute__((ext_vector_type(8)));
typedef float    f32x4 __attribute__((ext_vector_type(4)));

// ---------------- pass 1: per-block coarse histograms (no global atomics) ----
__global__ __launch_bounds__(256) void k_hist(const int* __restrict__ ei,
                                              int* __restrict__ hist) {
    __shared__ int h[NBIN];
    for (int i = threadIdx.x; i < NBIN; i += 256) h[i] = 0;
    __syncthreads();
    int base = blockIdx.x * EPB;
    for (int i = threadIdx.x; i < EPB; i += 256) {
        int d = ei[NE + base + i];
        atomicAdd(&h[d >> 7], 1);
    }
    __syncthreads();
    for (int i = threadIdx.x; i < NBIN; i += 256)
        hist[blockIdx.x * NBIN + i] = h[i];
}

// ---------------- scan A: per bin, scan counts across the 256 blocks --------
__global__ __launch_bounds__(256) void k_scanA(const int* __restrict__ hist,
                                               int* __restrict__ blockBase,
                                               int* __restrict__ binTotal) {
    __shared__ int s[256];
    int bin = blockIdx.x, t = threadIdx.x;
    int v = hist[t * NBIN + bin];
    s[t] = v; __syncthreads();
    for (int off = 1; off < 256; off <<= 1) {
        int x = (t >= off) ? s[t - off] : 0;
        __syncthreads();
        s[t] += x;
        __syncthreads();
    }
    blockBase[t * NBIN + bin] = s[t] - v;   // exclusive within bin
    if (t == 255) binTotal[bin] = s[255];
}

// ---------------- scan B: exclusive scan over bin totals ----------------
__global__ __launch_bounds__(1024) void k_scanB(const int* __restrict__ binTotal,
                                                int* __restrict__ binStart) {
    __shared__ int s[1024];
    int t = threadIdx.x;
    int v = (t < NBIN) ? binTotal[t] : 0;
    s[t] = v; __syncthreads();
    for (int off = 1; off < 1024; off <<= 1) {
        int x = (t >= off) ? s[t - off] : 0;
        __syncthreads();
        s[t] += x;
        __syncthreads();
    }
    if (t < NBIN) binStart[t] = s[t] - v;
    if (t == 1023) binStart[NBIN] = s[1023];   // == NE
}

// ---------------- pass 2: scatter edges into coarse buckets (LDS ranks) -----
// pay.x = src | (dst&127)<<17   (src < 2^17, key packed -> no separate array)
__global__ __launch_bounds__(256) void k_pass2(const int* __restrict__ ei,
                                               const float* __restrict__ ew,
                                               const int* __restrict__ binStart,
                                               const int* __restrict__ blockBase,
                                               int2* __restrict__ pay) {
    __shared__ int cur[NBIN];
    int blk = blockIdx.x;
    for (int i = threadIdx.x; i < NBIN; i += 256)
        cur[i] = binStart[i] + blockBase[blk * NBIN + i];
    __syncthreads();
    int base = blk * EPB;
    for (int i = threadIdx.x; i < EPB; i += 256) {
        int e = base + i;
        int d = ei[NE + e];
        int src = ei[e];
        float w = ew[e];
        int pos = atomicAdd(&cur[d >> 7], 1);
        pay[pos] = make_int2(src | ((d & 127) << 17), __float_as_int(w));
    }
}

// ---------------- pass 3: per-bucket local sort -> CSR + rowptr + dinv ------
__global__ __launch_bounds__(256) void k_pass3(const int* __restrict__ binStart,
                                               const int2* __restrict__ pay,
                                               int2* __restrict__ csr,
                                               int* __restrict__ rowptr,
                                               float* __restrict__ dinv) {
    __shared__ int2 sp[MAXB];
    __shared__ int hist[BPW], excl[BPW], cur[BPW];
    __shared__ float degw[BPW];
    int b = blockIdx.x, t = threadIdx.x;
    int s0 = binStart[b], s1 = binStart[b + 1];
    int n = s1 - s0;
    if (t < BPW) { hist[t] = 0; degw[t] = 0.f; }
    __syncthreads();
    for (int i = t; i < n; i += 256) {
        int2 p = pay[s0 + i];
        sp[i] = p;
        atomicAdd(&hist[(p.x >> 17) & 127], 1);
    }
    __syncthreads();
    if (t < BPW) excl[t] = hist[t];
    __syncthreads();
    for (int off = 1; off < BPW; off <<= 1) {
        int x = (t < BPW && t >= off) ? excl[t - off] : 0;
        __syncthreads();
        if (t < BPW) excl[t] += x;
        __syncthreads();
    }
    if (t < BPW) {
        int ex = excl[t] - hist[t];
        excl[t] = ex;
        cur[t] = ex;
    }
    __syncthreads();
    int node0 = b * BPW;
    if (t < BPW && node0 + t < NN) rowptr[node0 + t] = s0 + excl[t];
    if (b == NBIN - 1 && t == 0) rowptr[NN] = NE;
    for (int i = t; i < n; i += 256) {
        int2 p = sp[i];
        int k = (p.x >> 17) & 127;
        int pos = atomicAdd(&cur[k], 1);
        csr[s0 + pos] = make_int2(p.x & 0x1FFFF, p.y);
        atomicAdd(&degw[k], __int_as_float(p.y));
    }
    __syncthreads();
    if (t < BPW && node0 + t < NN) dinv[node0 + t] = rsqrtf(1.f + degw[t]);
}

// csr0[pos] = {emb_row(src) in bits 16-23, fp16(w*dinv[src]) in bits 0-15}
__global__ void k_mkcsr0(const int2* __restrict__ csr, const int* __restrict__ xidx,
                         const float* __restrict__ dinv, int* __restrict__ csr0) {
    int e = blockIdx.x * 256 + threadIdx.x;
    if (e < NE) {
        int2 c = csr[e];
        float wd = __int_as_float(c.y) * dinv[c.x];
        unsigned short h = __builtin_bit_cast(unsigned short, (_Float16)wd);
        csr0[e] = (xidx[c.x] << 16) | (int)h;
    }
}

// Wt[l][j][k] = fp16(W_l[k][j])  (transposed fp16 weights for MFMA B-fragments)
__global__ void k_wcvt(const float* __restrict__ conv_w, const float* __restrict__ lin1_w,
                       _Float16* __restrict__ wt) {
    int t = blockIdx.x * 256 + threadIdx.x;  // 3*16384
    int l = t >> 14, r = t & 16383;
    int j = r >> 7, k = r & 127;
    const float* src = (l < 2) ? (conv_w + (l + 1) * 16384) : lin1_w;
    wt[l * 16384 + j * 128 + k] = (_Float16)src[k * 128 + j];
}

// ---------------- embW0 = emb @ W0, stored fp16 (32KB, L1-resident) ----------
__global__ void k_embw(const float* __restrict__ emb, const float* __restrict__ w0,
                       __half2* __restrict__ ewh) {
    int t = blockIdx.x * 256 + threadIdx.x;  // 8192 threads
    int i = t >> 6, jp = t & 63;
    int j0 = jp * 2;
    float a0 = 0.f, a1 = 0.f;
    for (int k = 0; k < 128; k++) {
        float e = emb[i * 128 + k];
        a0 = fmaf(e, w0[k * 128 + j0], a0);
        a1 = fmaf(e, w0[k * 128 + j0 + 1], a1);
    }
    ewh[t] = __floats2half2_rn(a0, a1);
}

// ---------------- layer-0 aggregation: packed 4B csr0, L1-table gather ------
// Wave = 4 groups x 16 lanes, 8-wide main loop + guarded 4-wide tail (R6 form).
__global__ void k_agg0(const int* __restrict__ csr0, const int* __restrict__ rowptr,
                       const int* __restrict__ xidx, const float* __restrict__ dinv,
                       const _Float16* __restrict__ ewh, const float* __restrict__ bias,
                       _Float16* __restrict__ xout) {
    int wave = threadIdx.x >> 6, lane = threadIdx.x & 63;
    int g = lane >> 4, sub = lane & 15;
    int v = blockIdx.x * 4 + wave;
    if (v >= NN) return;
    int beg = rowptr[v], end = rowptr[v + 1];
    float acc[8];
#pragma unroll
    for (int i = 0; i < 8; i++) acc[i] = 0.f;
    int e = beg;
    while (e + 8 <= end) {
        int c0 = csr0[e + g];
        int c1 = csr0[e + 4 + g];
        f16x8 t0 = *reinterpret_cast<const f16x8*>(&ewh[((c0 >> 16) & 0xFF) * 128 + sub * 8]);
        f16x8 t1 = *reinterpret_cast<const f16x8*>(&ewh[((c1 >> 16) & 0xFF) * 128 + sub * 8]);
        float w0 = (float)__builtin_bit_cast(_Float16, (unsigned short)(c0 & 0xFFFF));
        float w1 = (float)__builtin_bit_cast(_Float16, (unsigned short)(c1 & 0xFFFF));
#pragma unroll
        for (int i = 0; i < 8; i++) acc[i] = fmaf(w0, (float)t0[i], acc[i]);
#pragma unroll
        for (int i = 0; i < 8; i++) acc[i] = fmaf(w1, (float)t1[i], acc[i]);
        e += 8;
    }
    for (; e < end; e += 4) {
        int idx = e + g;
        bool ok = idx < end;
        int c0 = csr0[ok ? idx : beg];
        float w0 = ok ? (float)__builtin_bit_cast(_Float16, (unsigned short)(c0 & 0xFFFF))
                      : 0.f;
        f16x8 t0 = *reinterpret_cast<const f16x8*>(&ewh[((c0 >> 16) & 0xFF) * 128 + sub * 8]);
#pragma unroll
        for (int i = 0; i < 8; i++) acc[i] = fmaf(w0, (float)t0[i], acc[i]);
    }
#pragma unroll
    for (int i = 0; i < 8; i++) {
        acc[i] += __shfl_down(acc[i], 32);
        acc[i] += __shfl_down(acc[i], 16);
    }
    if (g == 0) {
        float dv = dinv[v];
        f16x8 sf = *reinterpret_cast<const f16x8*>(&ewh[(size_t)xidx[v] * 128 + sub * 8]);
        float4 b0 = reinterpret_cast<const float4*>(bias)[sub * 2];
        float4 b1 = reinterpret_cast<const float4*>(bias)[sub * 2 + 1];
        float bb[8] = {b0.x, b0.y, b0.z, b0.w, b1.x, b1.y, b1.z, b1.w};
        f16x8 o;
#pragma unroll
        for (int i = 0; i < 8; i++) {
            float r = fmaf(dv, acc[i] + dv * (float)sf[i], bb[i]);
            o[i] = (_Float16)fmaxf(r, 0.f);
        }
        *reinterpret_cast<f16x8*>(&xout[(size_t)v * 128 + sub * 8]) = o;
    }
}

// ---------------- quad-edge aggregation core (best-measured R6 form) --------
template <int RELU>
__device__ __forceinline__ void agg_core(const _Float16* __restrict__ src16,
                                         const int2* __restrict__ csr,
                                         const int* __restrict__ rowptr,
                                         const float* __restrict__ dinv,
                                         const float* __restrict__ bias,
                                         _Float16* __restrict__ xout) {
    int wave = threadIdx.x >> 6, lane = threadIdx.x & 63;
    int g = lane >> 4, sub = lane & 15;
    int v = blockIdx.x * 4 + wave;
    if (v >= NN) return;
    int beg = rowptr[v], end = rowptr[v + 1];
    float acc[8];
#pragma unroll
    for (int i = 0; i < 8; i++) acc[i] = 0.f;
    int e = beg;
    while (e + 8 <= end) {
        int2 c0 = csr[e + g];
        int2 c1 = csr[e + 4 + g];
        f16x8 t0 = *reinterpret_cast<const f16x8*>(&src16[(size_t)c0.x * 128 + sub * 8]);
        f16x8 t1 = *reinterpret_cast<const f16x8*>(&src16[(size_t)c1.x * 128 + sub * 8]);
        float w0 = __int_as_float(c0.y), w1 = __int_as_float(c1.y);
#pragma unroll
        for (int i = 0; i < 8; i++) acc[i] = fmaf(w0, (float)t0[i], acc[i]);
#pragma unroll
        for (int i = 0; i < 8; i++) acc[i] = fmaf(w1, (float)t1[i], acc[i]);
        e += 8;
    }
    for (; e < end; e += 4) {
        int idx = e + g;
        bool ok = idx < end;
        int2 c0 = csr[ok ? idx : beg];
        float w0 = ok ? __int_as_float(c0.y) : 0.f;
        f16x8 t0 = *reinterpret_cast<const f16x8*>(&src16[(size_t)c0.x * 128 + sub * 8]);
#pragma unroll
        for (int i = 0; i < 8; i++) acc[i] = fmaf(w0, (float)t0[i], acc[i]);
    }
#pragma unroll
    for (int i = 0; i < 8; i++) {
        acc[i] += __shfl_down(acc[i], 32);
        acc[i] += __shfl_down(acc[i], 16);
    }
    if (g == 0) {
        float dv = dinv[v];
        f16x8 sf = *reinterpret_cast<const f16x8*>(&src16[(size_t)v * 128 + sub * 8]);
        float4 b0 = reinterpret_cast<const float4*>(bias)[sub * 2];
        float4 b1 = reinterpret_cast<const float4*>(bias)[sub * 2 + 1];
        float bb[8] = {b0.x, b0.y, b0.z, b0.w, b1.x, b1.y, b1.z, b1.w};
        f16x8 o;
#pragma unroll
        for (int i = 0; i < 8; i++) {
            float r = fmaf(dv, acc[i] + (float)sf[i], bb[i]);
            if (RELU) r = fmaxf(r, 0.f);
            o[i] = (_Float16)r;
        }
        *reinterpret_cast<f16x8*>(&xout[(size_t)v * 128 + sub * 8]) = o;
    }
}

__global__ void k_agg_r(const _Float16* __restrict__ y, const int* __restrict__ rowptr,
                        const int2* __restrict__ csr, const float* __restrict__ dinv,
                        const float* __restrict__ bias, _Float16* __restrict__ xout) {
    agg_core<1>(y, csr, rowptr, dinv, bias, xout);
}

__global__ void k_agg_n(const _Float16* __restrict__ y, const int* __restrict__ rowptr,
                        const int2* __restrict__ csr, const float* __restrict__ dinv,
                        const float* __restrict__ bias, _Float16* __restrict__ xout) {
    agg_core<0>(y, csr, rowptr, dinv, bias, xout);
}

// ---------------- MFMA fp16 GEMM: 64 rows/block, 4 waves, 16 rows/wave -------
// MODE 0: y[n][j] = fp16( dinv[n] * (A@W)[n][j] )
// MODE 1: h = relu(A@W + bias); out[n][0:2] = h @ w2 + b2
template <int MODE>
__global__ __launch_bounds__(256) void k_mgemm(const _Float16* __restrict__ A,
                                               const _Float16* __restrict__ Wt,
                                               const float* __restrict__ dinv,
                                               const float* __restrict__ bias,
                                               _Float16* __restrict__ yout,
                                               const float* __restrict__ w2,
                                               const float* __restrict__ b2,
                                               float* __restrict__ outf) {
    int wid = threadIdx.x >> 6, lane = threadIdx.x & 63;
    int lc = lane & 15, lg = lane >> 4;
    int arow = blockIdx.x * 64 + wid * 16 + lc;   // row this lane loads for A
    bool rok = arow < NN;

    f32x4 acc[8];
#pragma unroll
    for (int j = 0; j < 8; j++) acc[j] = (f32x4){0.f, 0.f, 0.f, 0.f};

#pragma unroll
    for (int kc = 0; kc < 4; kc++) {
        int k0 = kc * 32 + lg * 8;
        f16x8 a = {0, 0, 0, 0, 0, 0, 0, 0};
        if (rok) a = *reinterpret_cast<const f16x8*>(&A[arow * 128 + k0]);
#pragma unroll
        for (int j = 0; j < 8; j++) {
            f16x8 b = *reinterpret_cast<const f16x8*>(&Wt[(j * 16 + lc) * 128 + k0]);
            acc[j] = __builtin_amdgcn_mfma_f32_16x16x32_f16(a, b, acc[j], 0, 0, 0);
        }
    }

    int orow0 = blockIdx.x * 64 + wid * 16 + lg * 4;  // rows for regs r=0..3
    if (MODE == 0) {
        float dv[4];
#pragma unroll
        for (int r = 0; r < 4; r++)
            dv[r] = (orow0 + r < NN) ? dinv[orow0 + r] : 0.f;
#pragma unroll
        for (int j = 0; j < 8; j++) {
#pragma unroll
            for (int r = 0; r < 4; r++) {
                int orow = orow0 + r;
                if (orow < NN)
                    yout[orow * 128 + j * 16 + lc] = (_Float16)(dv[r] * acc[j][r]);
            }
        }
    } else {
        float bj[8], w0j[8], w1j[8];
#pragma unroll
        for (int j = 0; j < 8; j++) {
            int c = j * 16 + lc;
            bj[j] = bias[c];
            w0j[j] = w2[c * 2 + 0];
            w1j[j] = w2[c * 2 + 1];
        }
        float bb0 = b2[0], bb1 = b2[1];
#pragma unroll
        for (int r = 0; r < 4; r++) {
            float p0 = 0.f, p1 = 0.f;
#pragma unroll
            for (int j = 0; j < 8; j++) {
                float h = fmaxf(acc[j][r] + bj[j], 0.f);
                p0 = fmaf(h, w0j[j], p0);
                p1 = fmaf(h, w1j[j], p1);
            }
#pragma unroll
            for (int m = 1; m < 16; m <<= 1) {
                p0 += __shfl_xor(p0, m);
                p1 += __shfl_xor(p1, m);
            }
            int orow = orow0 + r;
            if (lc == 0 && orow < NN)
                *reinterpret_cast<float2*>(&outf[orow * 2]) =
                    make_float2(p0 + bb0, p1 + bb1);
        }
    }
}

extern "C" void kernel_launch(void* const* d_in, const int* in_sizes, int n_in,
                              void* d_out, int out_size, void* d_ws, size_t ws_size,
                              hipStream_t stream) {
    const int*   x_idx  = (const int*)d_in[0];
    const int*   ei     = (const int*)d_in[1];
    const float* ew     = (const float*)d_in[2];
    const float* emb    = (const float*)d_in[3];
    const float* conv_w = (const float*)d_in[4];
    const float* conv_b = (const float*)d_in[5];
    const float* lin1_w = (const float*)d_in[6];
    const float* lin1_b = (const float*)d_in[7];
    const float* lin2_w = (const float*)d_in[8];
    const float* lin2_b = (const float*)d_in[9];
    float* out = (float*)d_out;

    char* ws = (char*)d_ws;
    size_t off = 0;
    auto alloc = [&](size_t bytes) -> void* {
        void* p = ws + off;
        off += (bytes + 255) & ~(size_t)255;
        return p;
    };
    float*         dinv      = (float*)alloc(NN * 4);
    int*           rowptr    = (int*)alloc((NN + 1) * 4);
    int*           hist      = (int*)alloc((size_t)NHB * NBIN * 4);
    int*           blockBase = (int*)alloc((size_t)NHB * NBIN * 4);
    int*           binTotal  = (int*)alloc(NBIN * 4);
    int*           binStart  = (int*)alloc((NBIN + 1) * 4);
    int2*          pay       = (int2*)alloc((size_t)NE * 8);
    int2*          csr       = (int2*)alloc((size_t)NE * 8);
    int*           csr0      = (int*)alloc((size_t)NE * 4);
    _Float16*      ewh       = (_Float16*)alloc(128 * 128 * 2);
    _Float16*      wt        = (_Float16*)alloc(3 * 128 * 128 * 2);
    _Float16*      xbuf      = (_Float16*)alloc((size_t)NN * CC * 2);
    _Float16*      ybuf      = (_Float16*)alloc((size_t)NN * CC * 2);
    (void)ws_size;

    const int NBe = (NE + 255) / 256;       // 6250
    const int NBg = (NN + 63) / 64;         // 1563

    // CSR build: 2-level counting sort, no global atomics (separate kernels:
    // fused-prep variants measured 19us SLOWER, R11 vs R13)
    k_hist<<<NHB, 256, 0, stream>>>(ei, hist);
    k_scanA<<<NBIN, 256, 0, stream>>>(hist, blockBase, binTotal);
    k_scanB<<<1, 1024, 0, stream>>>(binTotal, binStart);
    k_pass2<<<NHB, 256, 0, stream>>>(ei, ew, binStart, blockBase, pay);
    k_pass3<<<NBIN, 256, 0, stream>>>(binStart, pay, csr, rowptr, dinv);
    k_mkcsr0<<<NBe, 256, 0, stream>>>(csr, x_idx, dinv, csr0);
    k_wcvt<<<192, 256, 0, stream>>>(conv_w, lin1_w, wt);

    // layer 0: ewh = fp16(emb @ W0); gather-aggregate from L1 table (4B csr0)
    k_embw<<<32, 256, 0, stream>>>(emb, conv_w, (__half2*)ewh);
    k_agg0<<<NN / 4, 256, 0, stream>>>(csr0, rowptr, x_idx, dinv, ewh,
                                       conv_b + 0 * CC, xbuf);
    // layer 1
    k_mgemm<0><<<NBg, 256, 0, stream>>>(xbuf, wt + 0 * 16384, dinv, nullptr, ybuf,
                                        nullptr, nullptr, nullptr);
    k_agg_r<<<NN / 4, 256, 0, stream>>>(ybuf, rowptr, csr, dinv, conv_b + 1 * CC, xbuf);
    // layer 2
    k_mgemm<0><<<NBg, 256, 0, stream>>>(xbuf, wt + 1 * 16384, dinv, nullptr, ybuf,
                                        nullptr, nullptr, nullptr);
    k_agg_n<<<NN / 4, 256, 0, stream>>>(ybuf, rowptr, csr, dinv, conv_b + 2 * CC, xbuf);
    // head: relu(x @ lin1_w + lin1_b) @ lin2_w + lin2_b, fused, MFMA
    k_mgemm<1><<<NBg, 256, 0, stream>>>(xbuf, wt + 2 * 16384, dinv, lin1_b, nullptr,
                                        lin2_w, lin2_b, out);
}